// Round 7
// baseline (332.382 us; speedup 1.0000x reference)
//
#include <hip/hip_runtime.h>
#include <math.h>

#define B_  16
#define T_  512
#define S_  1024
#define E_  1024
#define D_  1024

using short8   = __attribute__((ext_vector_type(8))) short;
using ushort4v = __attribute__((ext_vector_type(4))) unsigned short;
using float4v  = __attribute__((ext_vector_type(4))) float;

__device__ __forceinline__ unsigned short f2bf(float f) {
    unsigned u = __builtin_bit_cast(unsigned, f);
    u += 0x7fff + ((u >> 16) & 1);          // round-to-nearest-even
    return (unsigned short)(u >> 16);
}

__device__ __forceinline__ void gl_lds16(const void* g, void* l) {
    __builtin_amdgcn_global_load_lds(
        (const __attribute__((address_space(1))) void*)g,
        (__attribute__((address_space(3))) void*)l, 16, 0, 0);
}

// ---------------------------------------------------------------------------
// R0-validated MFMA GEMM tile body (shared by standalone + fused kernels).
// C[M,N] = A @ B^T, A/B bf16 row-major.  128x128 tile, BK=64 as two
// [128][32] subtiles (m97 lane mapping), global_load_lds w=16 staging,
// ds_read_b128 frags, 16x16x32 MFMA, one barrier pair per 64-k.
// A pre-offset by z*sA + row0*K; Bm by z*sB + col0*K; maskp by z*maskStride
// (or null); cOff = z*sC (element offset into Cp).
// ---------------------------------------------------------------------------
template<bool OUT_BF16, bool CMASK>
__device__ __forceinline__ void gemm_body(
    const unsigned short* __restrict__ A,
    const unsigned short* __restrict__ Bm,
    const float* __restrict__ maskp, void* __restrict__ Cp, long long cOff,
    int N, int K, int col0, int row0,
    unsigned short* Asl, unsigned short* Bsl)
{
    const int t    = threadIdx.x;
    const int lane = t & 63;
    const int wave = t >> 6;

    const int rs  = t >> 2;
    const int kcs = (t & 3) << 3;
    const unsigned ldsW = wave * 1024;

    const int wm = (wave >> 1) * 64;
    const int wn = (wave & 1) * 64;
    const int fr = lane & 15;
    const int fg = lane >> 4;

    float4v acc[4][4];
    #pragma unroll
    for (int i = 0; i < 4; ++i)
        #pragma unroll
        for (int j = 0; j < 4; ++j)
            acc[i][j] = (float4v)0.0f;

    for (int k0 = 0; k0 < K; k0 += 64) {
        #pragma unroll
        for (int j = 0; j < 2; ++j) {
            #pragma unroll
            for (int it = 0; it < 2; ++it) {
                const int r = rs + it * 64;
                const long long goff = (long long)r * K + k0 + j * 32 + kcs;
                const unsigned loff = j * 8192 + it * 4096 + ldsW;
                gl_lds16(A  + goff, (char*)Asl + loff);
                gl_lds16(Bm + goff, (char*)Bsl + loff);
            }
        }
        __syncthreads();

        short8 af[2][4], bf[2][4];
        #pragma unroll
        for (int j = 0; j < 2; ++j) {
            #pragma unroll
            for (int mi = 0; mi < 4; ++mi)
                af[j][mi] = *(const short8*)&Asl[j * 4096 + (wm + mi * 16 + fr) * 32 + fg * 8];
            #pragma unroll
            for (int ni = 0; ni < 4; ++ni)
                bf[j][ni] = *(const short8*)&Bsl[j * 4096 + (wn + ni * 16 + fr) * 32 + fg * 8];
        }
        #pragma unroll
        for (int j = 0; j < 2; ++j)
            #pragma unroll
            for (int mi = 0; mi < 4; ++mi)
                #pragma unroll
                for (int ni = 0; ni < 4; ++ni)
                    acc[mi][ni] = __builtin_amdgcn_mfma_f32_16x16x32_bf16(af[j][mi], bf[j][ni], acc[mi][ni], 0, 0, 0);
        __syncthreads();
    }

    float mv[4];
    #pragma unroll
    for (int ni = 0; ni < 4; ++ni) {
        int ocol = col0 + wn + ni * 16 + fr;
        mv[ni] = CMASK ? maskp[ocol] : 1.0f;
    }
    #pragma unroll
    for (int mi = 0; mi < 4; ++mi) {
        #pragma unroll
        for (int ni = 0; ni < 4; ++ni) {
            int ocol = col0 + wn + ni * 16 + fr;
            #pragma unroll
            for (int r = 0; r < 4; ++r) {
                int orow = row0 + wm + mi * 16 + fg * 4 + r;
                float v = acc[mi][ni][r] * mv[ni];
                if (OUT_BF16)
                    ((unsigned short*)Cp)[cOff + (long long)orow * N + ocol] = f2bf(v);
                else
                    ((float*)Cp)[cOff + (long long)orow * N + ocol] = v;
            }
        }
    }
}

// ---------------------------------------------------------------------------
// Standalone GEMM kernel (K4 + mid path) — wraps gemm_body, R0 geometry.
// ---------------------------------------------------------------------------
template<bool OUT_BF16, bool CMASK>
__global__ __launch_bounds__(256, 2)
void mfma_gemm_bf(const unsigned short* __restrict__ Ap,
                  const unsigned short* __restrict__ Bp,
                  const float* __restrict__ mask, void* __restrict__ Cp,
                  int N, int K,
                  long long sA, long long sB, long long sC, int maskStride)
{
    __shared__ unsigned short Asl[2 * 128 * 32];
    __shared__ unsigned short Bsl[2 * 128 * 32];
    const int z    = blockIdx.z;
    const int col0 = blockIdx.x * 128;
    const int row0 = blockIdx.y * 128;
    gemm_body<OUT_BF16, CMASK>(
        Ap + z * sA + (long long)row0 * K,
        Bp + z * sB + (long long)col0 * K,
        CMASK ? mask + (long long)z * maskStride : nullptr,
        Cp, z * sC, N, K, col0, row0, Asl, Bsl);
}

// ---------------------------------------------------------------------------
// L0: cast hidden (blocks [0,4096)) + transpose W (blocks [4096,4352)).
// ---------------------------------------------------------------------------
__global__ __launch_bounds__(256)
void prep0(const float* __restrict__ hidden, unsigned short* __restrict__ Hbf,
           const float* __restrict__ W, unsigned short* __restrict__ WT)
{
    __shared__ unsigned short tile[64][65];
    const int t = threadIdx.x;
    int bid = blockIdx.x;
    if (bid < 4096) {                      // cast hidden (8M elems, n8 = 1M)
        const int i = bid * 256 + t;
        float4 a = ((const float4*)hidden)[2 * i];
        float4 b = ((const float4*)hidden)[2 * i + 1];
        short8 o;
        o[0] = f2bf(a.x); o[1] = f2bf(a.y); o[2] = f2bf(a.z); o[3] = f2bf(a.w);
        o[4] = f2bf(b.x); o[5] = f2bf(b.y); o[6] = f2bf(b.z); o[7] = f2bf(b.w);
        ((short8*)Hbf)[i] = o;
        return;
    }
    bid -= 4096;                           // transpose W: 256 64x64 tiles
    const int c0 = (bid & 15) << 6;
    const int r0 = (bid >> 4) << 6;
    #pragma unroll
    for (int it = 0; it < 4; ++it) {
        int r  = (t >> 4) + it * 16;
        int c4 = (t & 15) << 2;
        float4 v = *(const float4*)&W[(long long)(r0 + r) * 1024 + c0 + c4];
        tile[r][c4 + 0] = f2bf(v.x);
        tile[r][c4 + 1] = f2bf(v.y);
        tile[r][c4 + 2] = f2bf(v.z);
        tile[r][c4 + 3] = f2bf(v.w);
    }
    __syncthreads();
    #pragma unroll
    for (int it = 0; it < 2; ++it) {
        int c  = (t >> 3) + it * 32;
        int r8 = (t & 7) << 3;
        short8 sv;
        #pragma unroll
        for (int j = 0; j < 8; ++j) sv[j] = (short)tile[r8 + j][c];
        *(short8*)&WT[(long long)(c0 + c) * 1024 + r0 + r8] = sv;
    }
}

// ---------------------------------------------------------------------------
// L1: K1 GEMM (G = Hbf @ WT^T, bf16 out) ∥ cast EO.
// Grid 8704 = 512 GEMM (bid%17==0; 8704/17=512 exactly) + 8192 cast blocks
// (2M short8 items).  Interleaved so CUs host GEMM + mem blocks
// concurrently (m114 MFMA/VMEM overlap).
// ---------------------------------------------------------------------------
__global__ __launch_bounds__(256, 2)
void k1_castEO(const unsigned short* __restrict__ Hbf,
               const unsigned short* __restrict__ WT,
               unsigned short* __restrict__ G,
               const float* __restrict__ eo, unsigned short* __restrict__ EObf)
{
    __shared__ unsigned short Asl[2 * 128 * 32];
    __shared__ unsigned short Bsl[2 * 128 * 32];
    const int bid = blockIdx.x;
    if (bid % 17 == 0) {
        const int g    = bid / 17;          // [0,512)
        const int row0 = (g >> 3) * 128;    // M = B*T = 8192
        const int col0 = (g & 7) * 128;     // N = E = 1024
        gemm_body<true, false>(
            Hbf + (long long)row0 * D_, WT + (long long)col0 * D_,
            nullptr, G, 0, E_, D_, col0, row0, Asl, Bsl);
    } else {
        const int i = (bid - bid / 17 - 1) * 256 + (int)threadIdx.x;  // [0,2M)
        if (i < B_ * S_ * E_ / 8) {
            float4 a = ((const float4*)eo)[2 * i];
            float4 b = ((const float4*)eo)[2 * i + 1];
            short8 o;
            o[0] = f2bf(a.x); o[1] = f2bf(a.y); o[2] = f2bf(a.z); o[3] = f2bf(a.w);
            o[4] = f2bf(b.x); o[5] = f2bf(b.y); o[6] = f2bf(b.z); o[7] = f2bf(b.w);
            ((short8*)EObf)[i] = o;
        }
    }
}

// ---------------------------------------------------------------------------
// L2: K2 GEMM (ae = mask * (G @ EObf^T), fp32 out) ∥ transpose EV.
// Grid 4608 = 512 GEMM (bid%9==0) + 4096 transpose tiles (16 x 256).
// ---------------------------------------------------------------------------
__global__ __launch_bounds__(256, 2)
void k2_transEV(const unsigned short* __restrict__ G,
                const unsigned short* __restrict__ EObf,
                const float* __restrict__ mask, float* __restrict__ ae,
                const float* __restrict__ ev, unsigned short* __restrict__ EVT)
{
    __shared__ unsigned short Asl[2 * 128 * 32];
    __shared__ unsigned short Bsl[2 * 128 * 32];
    const int bid = blockIdx.x;
    const int t = threadIdx.x;
    if (bid % 9 == 0) {
        const int g    = bid / 9;           // [0,512)
        const int z    = g >> 5;            // 16 batches
        const int rem  = g & 31;
        const int row0 = (rem >> 3) * 128;  // T = 512
        const int col0 = (rem & 7) * 128;   // S = 1024
        gemm_body<false, true>(
            G    + (long long)z * T_ * E_ + (long long)row0 * E_,
            EObf + (long long)z * S_ * E_ + (long long)col0 * E_,
            mask + (long long)z * S_,
            ae, (long long)z * T_ * S_, S_, E_, col0, row0, Asl, Bsl);
    } else {
        int idx = bid - bid / 9 - 1;        // [0,4096)
        const int z = idx >> 8;
        idx &= 255;
        const float* src = ev + (long long)z * S_ * D_;
        unsigned short* dst = EVT + (long long)z * D_ * S_;
        const int c0 = (idx & 15) << 6;
        const int r0 = (idx >> 4) << 6;
        auto tile = (unsigned short (*)[65])(void*)Asl;   // 4160 <= 8192 ushorts
        #pragma unroll
        for (int it = 0; it < 4; ++it) {
            int r  = (t >> 4) + it * 16;
            int c4 = (t & 15) << 2;
            float4 v = *(const float4*)&src[(long long)(r0 + r) * 1024 + c0 + c4];
            tile[r][c4 + 0] = f2bf(v.x);
            tile[r][c4 + 1] = f2bf(v.y);
            tile[r][c4 + 2] = f2bf(v.z);
            tile[r][c4 + 3] = f2bf(v.w);
        }
        __syncthreads();
        #pragma unroll
        for (int it = 0; it < 2; ++it) {
            int c  = (t >> 3) + it * 32;
            int r8 = (t & 7) << 3;
            short8 sv;
            #pragma unroll
            for (int j = 0; j < 8; ++j) sv[j] = (short)tile[r8 + j][c];
            *(short8*)&dst[(long long)(c0 + c) * 1024 + r0 + r8] = sv;
        }
    }
}

// ---------------------------------------------------------------------------
// Standalone cast / transpose kernels (mid path, R0-validated).
// ---------------------------------------------------------------------------
__global__ __launch_bounds__(256)
void cast_bf16(const float* __restrict__ src, unsigned short* __restrict__ dst, int n8)
{
    int i = blockIdx.x * 256 + threadIdx.x;
    if (i < n8) {
        float4 a = ((const float4*)src)[2 * i];
        float4 b = ((const float4*)src)[2 * i + 1];
        short8 o;
        o[0] = f2bf(a.x); o[1] = f2bf(a.y); o[2] = f2bf(a.z); o[3] = f2bf(a.w);
        o[4] = f2bf(b.x); o[5] = f2bf(b.y); o[6] = f2bf(b.z); o[7] = f2bf(b.w);
        ((short8*)dst)[i] = o;
    }
}

__global__ __launch_bounds__(256)
void transpose_cast(const float* __restrict__ src, unsigned short* __restrict__ dst,
                    int R, int C, long long sSrc, long long sDst)
{
    __shared__ unsigned short tile[64][65];
    const int z = blockIdx.z;
    src += (long long)z * sSrc;
    dst += (long long)z * sDst;
    const int c0 = blockIdx.x * 64;
    const int r0 = blockIdx.y * 64;
    const int t = threadIdx.x;

    #pragma unroll
    for (int it = 0; it < 4; ++it) {
        int r  = (t >> 4) + it * 16;
        int c4 = (t & 15) << 2;
        float4 v = *(const float4*)&src[(long long)(r0 + r) * C + c0 + c4];
        tile[r][c4 + 0] = f2bf(v.x);
        tile[r][c4 + 1] = f2bf(v.y);
        tile[r][c4 + 2] = f2bf(v.z);
        tile[r][c4 + 3] = f2bf(v.w);
    }
    __syncthreads();
    #pragma unroll
    for (int it = 0; it < 2; ++it) {
        int c  = (t >> 3) + it * 32;
        int r8 = (t & 7) << 3;
        short8 sv;
        #pragma unroll
        for (int j = 0; j < 8; ++j) sv[j] = (short)tile[r8 + j][c];
        *(short8*)&dst[(long long)(c0 + c) * R + r0 + r8] = sv;
    }
}

// ---------------------------------------------------------------------------
// Masked softmax; also writes a bf16 copy of the weights when wbf != nullptr.
// ---------------------------------------------------------------------------
__global__ __launch_bounds__(256)
void softmax_mask(const float* __restrict__ x, const float* __restrict__ mask,
                  float* __restrict__ w, unsigned short* __restrict__ wbf)
{
    const int row = blockIdx.x;
    const int b   = row >> 9;             // T_=512
    const float* xr = x    + (long long)row * S_;
    const float* mr = mask + (long long)b * S_;
    float*       wr = w    + (long long)row * S_;
    const int tid = threadIdx.x;

    float4 xv = ((const float4*)xr)[tid];
    float4 mv = ((const float4*)mr)[tid];

    float lmax = fmaxf(fmaxf(xv.x, xv.y), fmaxf(xv.z, xv.w));
    #pragma unroll
    for (int off = 32; off; off >>= 1)
        lmax = fmaxf(lmax, __shfl_xor(lmax, off, 64));

    __shared__ float red[4];
    const int wave = tid >> 6, lane = tid & 63;
    if (lane == 0) red[wave] = lmax;
    __syncthreads();
    const float rmax = fmaxf(fmaxf(red[0], red[1]), fmaxf(red[2], red[3]));

    float e0 = expf(xv.x - rmax) * mv.x;
    float e1 = expf(xv.y - rmax) * mv.y;
    float e2 = expf(xv.z - rmax) * mv.z;
    float e3 = expf(xv.w - rmax) * mv.w;

    float lsum = (e0 + e1) + (e2 + e3);
    #pragma unroll
    for (int off = 32; off; off >>= 1)
        lsum += __shfl_xor(lsum, off, 64);

    __syncthreads();
    if (lane == 0) red[wave] = lsum;
    __syncthreads();
    const float rsum = (red[0] + red[1]) + (red[2] + red[3]);
    const float inv = 1.0f / (rsum + 1e-6f);

    float4 o;
    o.x = e0 * inv; o.y = e1 * inv; o.z = e2 * inv; o.w = e3 * inv;
    ((float4*)wr)[tid] = o;
    if (wbf) {
        ushort4v u;
        u[0] = f2bf(o.x); u[1] = f2bf(o.y); u[2] = f2bf(o.z); u[3] = f2bf(o.w);
        ((ushort4v*)(wbf + (long long)row * S_))[tid] = u;
    }
}

// ---------------------------------------------------------------------------
// fp32 fallback GEMM — used only if d_ws is tiny.
// ---------------------------------------------------------------------------
constexpr int FBM = 64, FBN = 64, FBK = 16;
template<bool BT, bool CMASK>
__global__ __launch_bounds__(256)
void gemm_f32(const float* __restrict__ A, const float* __restrict__ Bm,
              const float* __restrict__ mask, float* __restrict__ C,
              int N_dim, int K_dim,
              long long sA, long long sB, long long sC, int maskStride)
{
    const int bz = blockIdx.z;
    A  += (long long)bz * sA;
    Bm += (long long)bz * sB;
    C  += (long long)bz * sC;
    __shared__ float As[FBK][FBM];
    __shared__ float Bs[FBK][FBN];
    const int tid  = threadIdx.x;
    const int row0 = blockIdx.y * FBM;
    const int col0 = blockIdx.x * FBN;
    const int lrow = tid >> 2;
    const int lk   = (tid & 3) << 2;
    const int bk = tid >> 4;
    const int bn = (tid & 15) << 2;
    const int tx = tid & 15;
    const int ty = tid >> 4;
    float acc[4][4] = {};
    const float* Aptr = A + (long long)(row0 + lrow) * K_dim + lk;
    const float* Bptr = BT ? (Bm + (long long)(col0 + lrow) * K_dim + lk)
                           : (Bm + (long long)bk * N_dim + col0 + bn);
    for (int k0 = 0; k0 < K_dim; k0 += FBK) {
        float4 av = *(const float4*)(Aptr + k0);
        As[lk + 0][lrow] = av.x; As[lk + 1][lrow] = av.y;
        As[lk + 2][lrow] = av.z; As[lk + 3][lrow] = av.w;
        if (BT) {
            float4 bv = *(const float4*)(Bptr + k0);
            Bs[lk + 0][lrow] = bv.x; Bs[lk + 1][lrow] = bv.y;
            Bs[lk + 2][lrow] = bv.z; Bs[lk + 3][lrow] = bv.w;
        } else {
            float4 bv = *(const float4*)(Bptr + (long long)k0 * N_dim);
            *(float4*)&Bs[bk][bn] = bv;
        }
        __syncthreads();
        #pragma unroll
        for (int k = 0; k < FBK; ++k) {
            float4 a4 = *(const float4*)&As[k][ty << 2];
            float4 b4 = *(const float4*)&Bs[k][tx << 2];
            float ar[4] = {a4.x, a4.y, a4.z, a4.w};
            float br[4] = {b4.x, b4.y, b4.z, b4.w};
            #pragma unroll
            for (int i = 0; i < 4; ++i)
                #pragma unroll
                for (int j = 0; j < 4; ++j)
                    acc[i][j] = fmaf(ar[i], br[j], acc[i][j]);
        }
        __syncthreads();
    }
    float mvv[4] = {1.f, 1.f, 1.f, 1.f};
    if (CMASK) {
        #pragma unroll
        for (int j = 0; j < 4; ++j)
            mvv[j] = mask[(long long)bz * maskStride + col0 + (tx << 2) + j];
    }
    #pragma unroll
    for (int i = 0; i < 4; ++i) {
        const int r = row0 + (ty << 2) + i;
        float4 o;
        o.x = acc[i][0] * mvv[0]; o.y = acc[i][1] * mvv[1];
        o.z = acc[i][2] * mvv[2]; o.w = acc[i][3] * mvv[3];
        *(float4*)&C[(long long)r * N_dim + col0 + (tx << 2)] = o;
    }
}

extern "C" void kernel_launch(void* const* d_in, const int* in_sizes, int n_in,
                              void* d_out, int out_size, void* d_ws, size_t ws_size,
                              hipStream_t stream)
{
    const float* hidden = (const float*)d_in[0];   // (B,T,D)
    const float* eo     = (const float*)d_in[1];   // (B,S,E)
    const float* ev     = (const float*)d_in[2];   // (B,S,D)
    const float* mask   = (const float*)d_in[3];   // (B,S)
    const float* W      = (const float*)d_in[4];   // (D,E)

    float* out = (float*)d_out;
    const long long CTX = (long long)B_ * T_ * D_;
    float* ctx = out;
    float* aw  = out + CTX;
    float* ae  = out + 2 * CTX;

    dim3 blk(256);
    const size_t MB = 1024ull * 1024ull;

    if (ws_size >= 100 * MB) {
        // De-aliased layout (all prep products coexist):
        //   Hbf [0,16) | WT [16,18) | G [18,34) | EObf [34,66) | EVT [66,98)
        //   AWbf aliases Hbf (Hbf dead after L1; AWbf written by softmax)
        char* ws = (char*)d_ws;
        unsigned short* Hbf  = (unsigned short*)(ws);
        unsigned short* WT   = (unsigned short*)(ws + 16 * MB);
        unsigned short* G    = (unsigned short*)(ws + 18 * MB);
        unsigned short* EObf = (unsigned short*)(ws + 34 * MB);
        unsigned short* EVT  = (unsigned short*)(ws + 66 * MB);
        unsigned short* AWbf = (unsigned short*)(ws);

        // L0: K1's dependencies only (cast H + transpose W)
        prep0<<<dim3(4352), blk, 0, stream>>>(hidden, Hbf, W, WT);

        // L1: K1 GEMM ∥ cast EO  (512 + 8192 blocks, interleaved 1:16)
        k1_castEO<<<dim3(8704), blk, 0, stream>>>(Hbf, WT, G, eo, EObf);

        // L2: K2 GEMM ∥ transpose EV  (512 + 4096 blocks, interleaved 1:8)
        k2_transEV<<<dim3(4608), blk, 0, stream>>>(G, EObf, mask, ae, ev, EVT);

        // L3: softmax -> aw (fp32) + AWbf (bf16)
        softmax_mask<<<dim3(B_ * T_), blk, 0, stream>>>(ae, mask, aw, AWbf);

        // L4: ctx = AWbf @ EVT^T
        mfma_gemm_bf<false, false><<<dim3(D_ / 128, T_ / 128, B_), blk, 0, stream>>>(
            AWbf, EVT, nullptr, ctx, D_, S_,
            (long long)T_ * S_, (long long)D_ * S_, (long long)T_ * D_, 0);
    } else if (ws_size >= 64 * MB) {
        // R0-validated 8-kernel flow with live-range aliasing:
        //   [0,16) Hbf -> EObf [0,32) after K1 | [16,18) WT | [16,48) EVT
        //   [48,64) G -> AWbf
        char* ws = (char*)d_ws;
        unsigned short* Hbf  = (unsigned short*)(ws);
        unsigned short* WT   = (unsigned short*)(ws + 16 * MB);
        unsigned short* EObf = (unsigned short*)(ws);
        unsigned short* EVT  = (unsigned short*)(ws + 16 * MB);
        unsigned short* G    = (unsigned short*)(ws + 48 * MB);
        unsigned short* AWbf = (unsigned short*)(ws + 48 * MB);

        cast_bf16<<<dim3((B_ * T_ * D_ / 8 + 255) / 256), blk, 0, stream>>>(
            hidden, Hbf, B_ * T_ * D_ / 8);
        transpose_cast<<<dim3(E_ / 64, D_ / 64, 1), blk, 0, stream>>>(
            W, WT, D_, E_, 0, 0);
        mfma_gemm_bf<true, false><<<dim3(E_ / 128, (B_ * T_) / 128, 1), blk, 0, stream>>>(
            Hbf, WT, nullptr, G, E_, D_, 0, 0, 0, 0);
        cast_bf16<<<dim3((B_ * S_ * E_ / 8 + 255) / 256), blk, 0, stream>>>(
            eo, EObf, B_ * S_ * E_ / 8);
        mfma_gemm_bf<false, true><<<dim3(S_ / 128, T_ / 128, B_), blk, 0, stream>>>(
            G, EObf, mask, ae, S_, E_,
            (long long)T_ * E_, (long long)S_ * E_, (long long)T_ * S_, S_);
        transpose_cast<<<dim3(D_ / 64, S_ / 64, B_), blk, 0, stream>>>(
            ev, EVT, S_, D_, (long long)S_ * D_, (long long)D_ * S_);
        softmax_mask<<<dim3(B_ * T_), blk, 0, stream>>>(ae, mask, aw, AWbf);
        mfma_gemm_bf<false, false><<<dim3(D_ / 128, T_ / 128, B_), blk, 0, stream>>>(
            AWbf, EVT, nullptr, ctx, D_, S_,
            (long long)T_ * S_, (long long)D_ * S_, (long long)T_ * D_, 0);
    } else {
        float* G = aw;
        gemm_f32<false, false><<<dim3(E_ / FBN, (B_ * T_) / FBM, 1), blk, 0, stream>>>(
            hidden, W, nullptr, G, E_, D_, 0, 0, 0, 0);
        gemm_f32<true, true><<<dim3(S_ / FBN, T_ / FBM, B_), blk, 0, stream>>>(
            G, eo, mask, ae, S_, E_,
            (long long)T_ * E_, (long long)S_ * E_, (long long)T_ * S_, S_);
        softmax_mask<<<dim3(B_ * T_), blk, 0, stream>>>(ae, mask, aw, nullptr);
        gemm_f32<false, false><<<dim3(D_ / FBN, T_ / FBM, B_), blk, 0, stream>>>(
            aw, ev, nullptr, ctx, D_, S_,
            (long long)T_ * S_, (long long)S_ * D_, (long long)T_ * D_, 0);
    }
}

// Round 8
// 325.282 us; speedup vs baseline: 1.0218x; 1.0218x over previous
//
#include <hip/hip_runtime.h>
#include <math.h>

#define B_  16
#define T_  512
#define S_  1024
#define E_  1024
#define D_  1024

using short8   = __attribute__((ext_vector_type(8))) short;
using ushort4v = __attribute__((ext_vector_type(4))) unsigned short;
using float4v  = __attribute__((ext_vector_type(4))) float;

__device__ __forceinline__ unsigned short f2bf(float f) {
    unsigned u = __builtin_bit_cast(unsigned, f);
    u += 0x7fff + ((u >> 16) & 1);          // round-to-nearest-even
    return (unsigned short)(u >> 16);
}

__device__ __forceinline__ void gl_lds16(const void* g, void* l) {
    __builtin_amdgcn_global_load_lds(
        (const __attribute__((address_space(1))) void*)g,
        (__attribute__((address_space(3))) void*)l, 16, 0, 0);
}

// ---------------------------------------------------------------------------
// Elementwise fp32 -> bf16 cast, 8 elements/thread.  (R0-validated)
// ---------------------------------------------------------------------------
__global__ __launch_bounds__(256)
void cast_bf16(const float* __restrict__ src, unsigned short* __restrict__ dst, int n8)
{
    int i = blockIdx.x * 256 + threadIdx.x;
    if (i < n8) {
        float4 a = ((const float4*)src)[2 * i];
        float4 b = ((const float4*)src)[2 * i + 1];
        short8 o;
        o[0] = f2bf(a.x); o[1] = f2bf(a.y); o[2] = f2bf(a.z); o[3] = f2bf(a.w);
        o[4] = f2bf(b.x); o[5] = f2bf(b.y); o[6] = f2bf(b.z); o[7] = f2bf(b.w);
        ((short8*)dst)[i] = o;
    }
}

// ---------------------------------------------------------------------------
// Transpose+cast: src (R x C) fp32 row-major -> dst (C x R) bf16 row-major.
// (R0-validated)
// ---------------------------------------------------------------------------
__global__ __launch_bounds__(256)
void transpose_cast(const float* __restrict__ src, unsigned short* __restrict__ dst,
                    int R, int C, long long sSrc, long long sDst)
{
    __shared__ unsigned short tile[64][65];
    const int z = blockIdx.z;
    src += (long long)z * sSrc;
    dst += (long long)z * sDst;
    const int c0 = blockIdx.x * 64;
    const int r0 = blockIdx.y * 64;
    const int t = threadIdx.x;

    #pragma unroll
    for (int it = 0; it < 4; ++it) {
        int r  = (t >> 4) + it * 16;
        int c4 = (t & 15) << 2;
        float4 v = *(const float4*)&src[(long long)(r0 + r) * C + c0 + c4];
        tile[r][c4 + 0] = f2bf(v.x);
        tile[r][c4 + 1] = f2bf(v.y);
        tile[r][c4 + 2] = f2bf(v.z);
        tile[r][c4 + 3] = f2bf(v.w);
    }
    __syncthreads();
    #pragma unroll
    for (int it = 0; it < 2; ++it) {
        int c  = (t >> 3) + it * 32;
        int r8 = (t & 7) << 3;
        short8 sv;
        #pragma unroll
        for (int j = 0; j < 8; ++j) sv[j] = (short)tile[r8 + j][c];
        *(short8*)&dst[(long long)(c0 + c) * R + r0 + r8] = sv;
    }
}

// ---------------------------------------------------------------------------
// MFMA GEMM v2: C[M,N] = A @ B^T, A (M,K) bf16, B (N,K) bf16, row-major.
// 128x128 tile, BK=64 (two [128][32] subtiles, m97 lane mapping),
// global_load_lds w=16, ds_read_b128 frags, 16x16x32 MFMA.
// ROUND 8 change (T4, counted vmcnt): double-buffered LDS (R1-verified
// mapping) with raw s_barrier + counted `s_waitcnt vmcnt(8)` so the 8
// gl_lds of the NEXT tile stay in flight across the barrier; we wait only
// on loads issued one full iteration earlier (~700cy ago -> near-zero
// stall) instead of draining vmcnt(0) on loads issued immediately before
// (~600-900cy stall, the measured MfmaUtil=9.5% culprit).  Race safety:
//   barrier1 after each wave's vmcnt(8)  => all waves' buf writes landed
//   barrier2 after lgkmcnt(0) ds_reads   => all reads retired before any
//                                           wave's next STAGE overwrites
// MFMA is register-only after barrier2 and overlaps the next STAGE issue.
// ---------------------------------------------------------------------------
template<bool OUT_BF16, bool CMASK>
__global__ __launch_bounds__(256, 2)
void mfma_gemm_bf(const unsigned short* __restrict__ Ap,
                  const unsigned short* __restrict__ Bp,
                  const float* __restrict__ mask, void* __restrict__ Cp,
                  int N, int K,
                  long long sA, long long sB, long long sC, int maskStride)
{
    __shared__ unsigned short Asl[2][2 * 128 * 32];   // 32 KB
    __shared__ unsigned short Bsl[2][2 * 128 * 32];   // 32 KB (64 KB total)

    const int z    = blockIdx.z;
    const int col0 = blockIdx.x * 128;
    const int row0 = blockIdx.y * 128;
    const int t    = threadIdx.x;
    const int lane = t & 63;
    const int wave = t >> 6;

    const unsigned short* A  = Ap + z * sA + (long long)row0 * K;
    const unsigned short* Bm = Bp + z * sB + (long long)col0 * K;

    // staging map (m97-validated): chunk c = it*256 + t covers row c>>2,
    // k-chunk (c&3)*8 of a [128][32] subtile; LDS dest byte =
    // j*8192 + it*4096 + wave*1024 + lane*16.
    const int rs  = t >> 2;
    const int kcs = (t & 3) << 3;
    const unsigned ldsW = wave * 1024;

    const int wm = (wave >> 1) * 64;
    const int wn = (wave & 1) * 64;
    const int fr = lane & 15;
    const int fg = lane >> 4;

    float4v acc[4][4];
    #pragma unroll
    for (int i = 0; i < 4; ++i)
        #pragma unroll
        for (int j = 0; j < 4; ++j)
            acc[i][j] = (float4v)0.0f;

    // 8 gl_lds per thread per call (4 A + 4 B)
    auto STAGE = [&](int bufi, int k0) {
        #pragma unroll
        for (int j = 0; j < 2; ++j)
            #pragma unroll
            for (int it = 0; it < 2; ++it) {
                const int r = rs + it * 64;
                const long long goff = (long long)r * K + k0 + j * 32 + kcs;
                const unsigned loff = j * 8192 + it * 4096 + ldsW;
                gl_lds16(A  + goff, (char*)&Asl[bufi][0] + loff);
                gl_lds16(Bm + goff, (char*)&Bsl[bufi][0] + loff);
            }
    };

    STAGE(0, 0);                       // prologue: 8 loads in flight
    int buf = 0;
    const int NT = K >> 6;             // 16 for all call sites

    for (int ti = 0; ti < NT; ++ti) {
        if (ti + 1 < NT) {
            STAGE(buf ^ 1, (ti + 1) << 6);                  // +8 -> 16 in flight
            asm volatile("s_waitcnt vmcnt(8)" ::: "memory"); // oldest 8 (= buf) done
        } else {
            asm volatile("s_waitcnt vmcnt(0)" ::: "memory"); // last tile: drain
        }
        __builtin_amdgcn_s_barrier();       // all waves' buf writes visible
        asm volatile("" ::: "memory");

        short8 af[2][4], bfv[2][4];
        #pragma unroll
        for (int j = 0; j < 2; ++j) {
            #pragma unroll
            for (int mi = 0; mi < 4; ++mi)
                af[j][mi]  = *(const short8*)&Asl[buf][j * 4096 + (wm + mi * 16 + fr) * 32 + fg * 8];
            #pragma unroll
            for (int ni = 0; ni < 4; ++ni)
                bfv[j][ni] = *(const short8*)&Bsl[buf][j * 4096 + (wn + ni * 16 + fr) * 32 + fg * 8];
        }
        asm volatile("s_waitcnt lgkmcnt(0)" ::: "memory");   // my reads retired
        __builtin_amdgcn_sched_barrier(0);                   // rule 18 fence
        __builtin_amdgcn_s_barrier();       // all waves done reading buf
        asm volatile("" ::: "memory");

        #pragma unroll
        for (int j = 0; j < 2; ++j)
            #pragma unroll
            for (int mi = 0; mi < 4; ++mi)
                #pragma unroll
                for (int ni = 0; ni < 4; ++ni)
                    acc[mi][ni] = __builtin_amdgcn_mfma_f32_16x16x32_bf16(af[j][mi], bfv[j][ni], acc[mi][ni], 0, 0, 0);
        buf ^= 1;
    }

    float mv[4];
    #pragma unroll
    for (int ni = 0; ni < 4; ++ni) {
        int ocol = col0 + wn + ni * 16 + fr;
        mv[ni] = CMASK ? mask[(long long)z * maskStride + ocol] : 1.0f;
    }
    #pragma unroll
    for (int mi = 0; mi < 4; ++mi) {
        #pragma unroll
        for (int ni = 0; ni < 4; ++ni) {
            int ocol = col0 + wn + ni * 16 + fr;
            #pragma unroll
            for (int r = 0; r < 4; ++r) {
                int orow = row0 + wm + mi * 16 + fg * 4 + r;
                float v = acc[mi][ni][r] * mv[ni];
                if (OUT_BF16)
                    ((unsigned short*)Cp)[z * sC + (long long)orow * N + ocol] = f2bf(v);
                else
                    ((float*)Cp)[z * sC + (long long)orow * N + ocol] = v;
            }
        }
    }
}

// ---------------------------------------------------------------------------
// Masked softmax; also writes a bf16 copy of the weights when wbf != nullptr.
// (R0-validated)
// ---------------------------------------------------------------------------
__global__ __launch_bounds__(256)
void softmax_mask(const float* __restrict__ x, const float* __restrict__ mask,
                  float* __restrict__ w, unsigned short* __restrict__ wbf)
{
    const int row = blockIdx.x;
    const int b   = row >> 9;             // T_=512
    const float* xr = x    + (long long)row * S_;
    const float* mr = mask + (long long)b * S_;
    float*       wr = w    + (long long)row * S_;
    const int tid = threadIdx.x;

    float4 xv = ((const float4*)xr)[tid];
    float4 mv = ((const float4*)mr)[tid];

    float lmax = fmaxf(fmaxf(xv.x, xv.y), fmaxf(xv.z, xv.w));
    #pragma unroll
    for (int off = 32; off; off >>= 1)
        lmax = fmaxf(lmax, __shfl_xor(lmax, off, 64));

    __shared__ float red[4];
    const int wave = tid >> 6, lane = tid & 63;
    if (lane == 0) red[wave] = lmax;
    __syncthreads();
    const float rmax = fmaxf(fmaxf(red[0], red[1]), fmaxf(red[2], red[3]));

    float e0 = expf(xv.x - rmax) * mv.x;
    float e1 = expf(xv.y - rmax) * mv.y;
    float e2 = expf(xv.z - rmax) * mv.z;
    float e3 = expf(xv.w - rmax) * mv.w;

    float lsum = (e0 + e1) + (e2 + e3);
    #pragma unroll
    for (int off = 32; off; off >>= 1)
        lsum += __shfl_xor(lsum, off, 64);

    __syncthreads();
    if (lane == 0) red[wave] = lsum;
    __syncthreads();
    const float rsum = (red[0] + red[1]) + (red[2] + red[3]);
    const float inv = 1.0f / (rsum + 1e-6f);

    float4 o;
    o.x = e0 * inv; o.y = e1 * inv; o.z = e2 * inv; o.w = e3 * inv;
    ((float4*)wr)[tid] = o;
    if (wbf) {
        ushort4v u;
        u[0] = f2bf(o.x); u[1] = f2bf(o.y); u[2] = f2bf(o.z); u[3] = f2bf(o.w);
        ((ushort4v*)(wbf + (long long)row * S_))[tid] = u;
    }
}

// ---------------------------------------------------------------------------
// fp32 fallback GEMM — used only if d_ws is tiny.
// ---------------------------------------------------------------------------
constexpr int FBM = 64, FBN = 64, FBK = 16;
template<bool BT, bool CMASK>
__global__ __launch_bounds__(256)
void gemm_f32(const float* __restrict__ A, const float* __restrict__ Bm,
              const float* __restrict__ mask, float* __restrict__ C,
              int N_dim, int K_dim,
              long long sA, long long sB, long long sC, int maskStride)
{
    const int bz = blockIdx.z;
    A  += (long long)bz * sA;
    Bm += (long long)bz * sB;
    C  += (long long)bz * sC;
    __shared__ float As[FBK][FBM];
    __shared__ float Bs[FBK][FBN];
    const int tid  = threadIdx.x;
    const int row0 = blockIdx.y * FBM;
    const int col0 = blockIdx.x * FBN;
    const int lrow = tid >> 2;
    const int lk   = (tid & 3) << 2;
    const int bk = tid >> 4;
    const int bn = (tid & 15) << 2;
    const int tx = tid & 15;
    const int ty = tid >> 4;
    float acc[4][4] = {};
    const float* Aptr = A + (long long)(row0 + lrow) * K_dim + lk;
    const float* Bptr = BT ? (Bm + (long long)(col0 + lrow) * K_dim + lk)
                           : (Bm + (long long)bk * N_dim + col0 + bn);
    for (int k0 = 0; k0 < K_dim; k0 += FBK) {
        float4 av = *(const float4*)(Aptr + k0);
        As[lk + 0][lrow] = av.x; As[lk + 1][lrow] = av.y;
        As[lk + 2][lrow] = av.z; As[lk + 3][lrow] = av.w;
        if (BT) {
            float4 bv = *(const float4*)(Bptr + k0);
            Bs[lk + 0][lrow] = bv.x; Bs[lk + 1][lrow] = bv.y;
            Bs[lk + 2][lrow] = bv.z; Bs[lk + 3][lrow] = bv.w;
        } else {
            float4 bv = *(const float4*)(Bptr + (long long)k0 * N_dim);
            *(float4*)&Bs[bk][bn] = bv;
        }
        __syncthreads();
        #pragma unroll
        for (int k = 0; k < FBK; ++k) {
            float4 a4 = *(const float4*)&As[k][ty << 2];
            float4 b4 = *(const float4*)&Bs[k][tx << 2];
            float ar[4] = {a4.x, a4.y, a4.z, a4.w};
            float br[4] = {b4.x, b4.y, b4.z, b4.w};
            #pragma unroll
            for (int i = 0; i < 4; ++i)
                #pragma unroll
                for (int j = 0; j < 4; ++j)
                    acc[i][j] = fmaf(ar[i], br[j], acc[i][j]);
        }
        __syncthreads();
    }
    float mvv[4] = {1.f, 1.f, 1.f, 1.f};
    if (CMASK) {
        #pragma unroll
        for (int j = 0; j < 4; ++j)
            mvv[j] = mask[(long long)bz * maskStride + col0 + (tx << 2) + j];
    }
    #pragma unroll
    for (int i = 0; i < 4; ++i) {
        const int r = row0 + (ty << 2) + i;
        float4 o;
        o.x = acc[i][0] * mvv[0]; o.y = acc[i][1] * mvv[1];
        o.z = acc[i][2] * mvv[2]; o.w = acc[i][3] * mvv[3];
        *(float4*)&C[(long long)r * N_dim + col0 + (tx << 2)] = o;
    }
}

extern "C" void kernel_launch(void* const* d_in, const int* in_sizes, int n_in,
                              void* d_out, int out_size, void* d_ws, size_t ws_size,
                              hipStream_t stream)
{
    const float* hidden = (const float*)d_in[0];   // (B,T,D)
    const float* eo     = (const float*)d_in[1];   // (B,S,E)
    const float* ev     = (const float*)d_in[2];   // (B,S,D)
    const float* mask   = (const float*)d_in[3];   // (B,S)
    const float* W      = (const float*)d_in[4];   // (D,E)

    float* out = (float*)d_out;
    const long long CTX = (long long)B_ * T_ * D_;
    float* ctx = out;
    float* aw  = out + CTX;
    float* ae  = out + 2 * CTX;

    dim3 blk(256);
    const size_t MB = 1024ull * 1024ull;
    const size_t NEED_FAST = 64 * MB;

    if (ws_size >= NEED_FAST) {
        // R0-validated serial chain + live-range aliasing:
        //   [0,16) Hbf -> EObf [0,32) after K1 | [16,18) WT | [16,48) EVT
        //   [48,64) G -> AWbf
        char* ws = (char*)d_ws;
        unsigned short* Hbf  = (unsigned short*)(ws);
        unsigned short* WT   = (unsigned short*)(ws + 16 * MB);
        unsigned short* EObf = (unsigned short*)(ws);
        unsigned short* EVT  = (unsigned short*)(ws + 16 * MB);
        unsigned short* G    = (unsigned short*)(ws + 48 * MB);
        unsigned short* AWbf = (unsigned short*)(ws + 48 * MB);

        cast_bf16<<<dim3((B_ * T_ * D_ / 8 + 255) / 256), blk, 0, stream>>>(
            hidden, Hbf, B_ * T_ * D_ / 8);
        transpose_cast<<<dim3(E_ / 64, D_ / 64, 1), blk, 0, stream>>>(
            W, WT, D_, E_, 0, 0);

        // K1: G = Hbf @ WT^T  -> bf16
        mfma_gemm_bf<true, false><<<dim3(E_ / 128, (B_ * T_) / 128, 1), blk, 0, stream>>>(
            Hbf, WT, nullptr, G, E_, D_, 0, 0, 0, 0);

        cast_bf16<<<dim3((B_ * S_ * E_ / 8 + 255) / 256), blk, 0, stream>>>(
            eo, EObf, B_ * S_ * E_ / 8);

        // K2: ae[b,t,s] = mask[b,s] * (G[b,t,:] . EObf[b,s,:])
        mfma_gemm_bf<false, true><<<dim3(S_ / 128, T_ / 128, B_), blk, 0, stream>>>(
            G, EObf, mask, ae, S_, E_,
            (long long)T_ * E_, (long long)S_ * E_, (long long)T_ * S_, S_);

        // EVt[b][d][s] = EV[b][s][d]
        transpose_cast<<<dim3(D_ / 64, S_ / 64, B_), blk, 0, stream>>>(
            ev, EVT, S_, D_, (long long)S_ * D_, (long long)D_ * S_);

        // K3: softmax -> aw (fp32) + AWbf (bf16, aliases G)
        softmax_mask<<<dim3(B_ * T_), blk, 0, stream>>>(ae, mask, aw, AWbf);

        // K4: ctx = AWbf @ EVT^T
        mfma_gemm_bf<false, false><<<dim3(D_ / 128, T_ / 128, B_), blk, 0, stream>>>(
            AWbf, EVT, nullptr, ctx, D_, S_,
            (long long)T_ * S_, (long long)D_ * S_, (long long)T_ * D_, 0);
    } else {
        float* G = aw;
        gemm_f32<false, false><<<dim3(E_ / FBN, (B_ * T_) / FBM, 1), blk, 0, stream>>>(
            hidden, W, nullptr, G, E_, D_, 0, 0, 0, 0);
        gemm_f32<true, true><<<dim3(S_ / FBN, T_ / FBM, B_), blk, 0, stream>>>(
            G, eo, mask, ae, S_, E_,
            (long long)T_ * E_, (long long)S_ * E_, (long long)T_ * S_, S_);
        softmax_mask<<<dim3(B_ * T_), blk, 0, stream>>>(ae, mask, aw, nullptr);
        gemm_f32<false, false><<<dim3(D_ / FBN, T_ / FBM, B_), blk, 0, stream>>>(
            aw, ev, nullptr, ctx, D_, S_,
            (long long)T_ * S_, (long long)S_ * D_, (long long)T_ * D_, 0);
    }
}